// Round 8
// baseline (154.752 us; speedup 1.0000x reference)
//
#include <hip/hip_runtime.h>
#include <hip/hip_bf16.h>

#define N_NODES 50000
#define N_EDGES 800000
#define D 128

#define SB     3125      // scatter bucket = dst>>4 (16 nodes); 50000 = 3125*16
#define SBP    3200      // padded bucket count (scan/counter arrays)
#define WCAP16 384       // window slots/bucket; lambda=256, +8 sigma
#define EPB    8192      // edges per scatter block
#define SBLK   98        // ceil(800000/8192); last block 5376 edges
#define XBLK   800       // conversion blocks (1024 thr, 2 float4 each)

using bf16x8 = __attribute__((ext_vector_type(8))) short;   // 8 bf16 (4 VGPRs)
using u16x8  = __attribute__((ext_vector_type(8))) unsigned short;
using f32x4  = __attribute__((ext_vector_type(4))) float;   // MFMA C/D

static __device__ __forceinline__ ushort f2bf(float f) {
    __hip_bfloat16 h = __float2bfloat16(f);   // RNE
    return *reinterpret_cast<ushort*>(&h);
}
static __device__ __forceinline__ float bf2f(ushort u) {
    return __uint_as_float(((unsigned)u) << 16);
}

// ---------------------------------------------------------------------------
// ws layout (~30.6 MB): bcnt[SBP*16] int (200 KB, one counter per 64B line),
// pairs[SB*WCAP16] u32 (4.8 MB, src | dst<<16, sorted to 16-node buckets),
// xb (bf16 x, 12.8 MB), aggb (bf16 agg, 12.8 MB).
// r7 lessons: counting-sort killed the scattered-store wall; the remaining
// pig was the fused gather (~55us, capped at 2-4 loads in flight). This
// round: 16-node-bucket sort -> per-WAVE ballot compaction (no LDS CSR),
// one wave per node with 16 rows in flight, standalone verified GEMM.
// ---------------------------------------------------------------------------

// Role-split fused kernel: blocks [0,SBLK) counting-sort scatter; blocks
// [SBLK, SBLK+XBLK) stream x -> bf16. Runs concurrently on device.
__global__ void __launch_bounds__(1024)
convert_scatter(const float4* __restrict__ x4, ushort* __restrict__ xb,
                const int* __restrict__ src, const int* __restrict__ dst,
                int* __restrict__ bcnt, unsigned* __restrict__ pairs) {
    __shared__ int      A[SBP];            // scan -> delta      (12.8 KB)
    __shared__ int      B[SBP];            // cnt -> lcur        (12.8 KB)
    __shared__ unsigned payload[EPB];      // sorted edges       (32 KB)
    const int tid = threadIdx.x;

    if (blockIdx.x >= SBLK) {
        // ---- conversion role: 2 float4 per thread, fully covers 1.6M ----
        const int gt = (blockIdx.x - SBLK) * 1024 + tid;
        const int total4 = N_NODES * D / 4;
        const int stride = XBLK * 1024;    // 819200
        for (int j = gt; j < total4; j += stride) {
            float4 v = x4[j];
            ushort4 u = make_ushort4(f2bf(v.x), f2bf(v.y), f2bf(v.z), f2bf(v.w));
            *(ushort4*)(xb + (size_t)j * 4) = u;
        }
        return;
    }

    // ---- scatter role: LDS counting sort to 16-node buckets ----
    const int base = blockIdx.x * EPB;
    int nblk = N_EDGES - base;
    if (nblk > EPB) nblk = EPB;

    for (int i = tid; i < SBP; i += 1024) A[i] = 0;
    __syncthreads();

    unsigned pk[8];
#pragma unroll
    for (int k = 0; k < 8; ++k) {
        int i = k * 1024 + tid;
        pk[k] = 0xFFFFFFFFu;               // sentinel (never dereferenced)
        if (i < nblk) {
            int e = base + i;
            pk[k] = (unsigned)src[e] | ((unsigned)dst[e] << 16);
            atomicAdd(&A[pk[k] >> 20], 1);     // bucket = dst>>4
        }
    }
    __syncthreads();

    for (int i = tid; i < SBP; i += 1024) B[i] = A[i];   // save counts
    __syncthreads();

    // Hillis-Steele inclusive scan over 3200 (4 elems/thread, 12 steps)
    for (int off = 1; off < SBP; off <<= 1) {
        int t[4];
#pragma unroll
        for (int k = 0; k < 4; ++k) {
            int i = tid + k * 1024;
            t[k] = (i < SBP && i >= off) ? A[i - off] : 0;
        }
        __syncthreads();
#pragma unroll
        for (int k = 0; k < 4; ++k) {
            int i = tid + k * 1024;
            if (i < SBP) A[i] += t[k];
        }
        __syncthreads();
    }

    // per-bucket: claim global run, build delta (addr = lds_pos + delta)
    for (int i = tid; i < SBP; i += 1024) {
        int incl = A[i], cnt = B[i];
        int excl = incl - cnt;
        int gb = cnt ? atomicAdd(&bcnt[i * 16], cnt) : 0;  // padded counter
        A[i] = i * WCAP16 + gb - excl;     // delta
        B[i] = excl;                       // lcur
    }
    __syncthreads();

#pragma unroll
    for (int k = 0; k < 8; ++k) {          // place into LDS (bucket-sorted)
        unsigned p = pk[k];
        if (p != 0xFFFFFFFFu) {
            int pos = atomicAdd(&B[p >> 20], 1);
            payload[pos] = p;
        }
    }
    __syncthreads();

#pragma unroll
    for (int k = 0; k < 8; ++k) {          // coalesced run writes
        int i = k * 1024 + tid;
        if (i < nblk) {
            unsigned p = payload[i];
            int bkt = (int)(p >> 20);
            int addr = i + A[bkt];
            if (addr < (bkt + 1) * WCAP16)     // 8-sigma guard, never trips
                pairs[addr] = p;
        }
    }
}

// ---------------------------------------------------------------------------
// Gather: ONE WAVE PER NODE (12500 blocks x 256 = 4 waves/block).
// Wave filters its 16-node bucket window by ballot-compaction (no LDS CSR,
// no barriers), then quarter-wave row gather with 16 rows in flight.
// ---------------------------------------------------------------------------
__global__ void __launch_bounds__(256)
gather_sum(const unsigned* __restrict__ pairs, const int* __restrict__ bcnt,
           const ushort* __restrict__ xb, ushort* __restrict__ aggb) {
    __shared__ ushort lsw[4][64];          // per-wave compacted src indices
    const int tid  = threadIdx.x;
    const int wv   = tid >> 6;
    const int lane = tid & 63;
    const int node = blockIdx.x * 4 + wv;  // < 50000 (12500*4 exact)
    const int b16  = node >> 4;
    const unsigned sub = (unsigned)(node & 15);

    int cnt = bcnt[b16 * 16];
    if (cnt > WCAP16) cnt = WCAP16;
    const unsigned* wp = pairs + (size_t)b16 * WCAP16;

    // ---- ballot compaction: 6 coalesced window reads ----
    int deg = 0;
#pragma unroll
    for (int k = 0; k < 6; ++k) {          // 6*64 = 384 = WCAP16
        int i = k * 64 + lane;
        unsigned p = (i < cnt) ? wp[i] : 0u;
        bool m = (i < cnt) && (((p >> 16) & 15u) == sub);
        unsigned long long mask = __ballot(m);
        if (m) {
            int rank = deg + __popcll(mask & ((1ULL << lane) - 1ULL));
            if (rank < 64) lsw[wv][rank] = (ushort)(p & 0xFFFFu);
        }
        deg += (int)__popcll(mask);
    }
    if (deg > 64) deg = 64;                // P(deg>64)~1e-18

    // ---- gather: quarter-wave rows (16 lanes x 16B = 256B row), 4 rows/
    // step, unroll 4 => 16 rows in flight per wave ----
    const int q  = lane >> 4;
    const int c8 = (lane & 15) << 3;
    const ushort* xbb = xb + c8;

    float acc[8];
#pragma unroll
    for (int j = 0; j < 8; ++j) acc[j] = 0.f;

    const int full = deg >> 2;
    int t = 0;
    for (; t + 4 <= full; t += 4) {
        int s0 = lsw[wv][4 * t + q];
        int s1 = lsw[wv][4 * t + 4 + q];
        int s2 = lsw[wv][4 * t + 8 + q];
        int s3 = lsw[wv][4 * t + 12 + q];
        u16x8 u0 = *(const u16x8*)(xbb + (size_t)s0 * D);
        u16x8 u1 = *(const u16x8*)(xbb + (size_t)s1 * D);
        u16x8 u2 = *(const u16x8*)(xbb + (size_t)s2 * D);
        u16x8 u3 = *(const u16x8*)(xbb + (size_t)s3 * D);
#pragma unroll
        for (int j = 0; j < 8; ++j)
            acc[j] += (bf2f(u0[j]) + bf2f(u1[j])) + (bf2f(u2[j]) + bf2f(u3[j]));
    }
    for (; t < full; ++t) {
        int s = lsw[wv][4 * t + q];
        u16x8 u = *(const u16x8*)(xbb + (size_t)s * D);
#pragma unroll
        for (int j = 0; j < 8; ++j) acc[j] += bf2f(u[j]);
    }
    const int rem = deg & 3;
    if (rem && q < rem) {
        int s = lsw[wv][4 * full + q];
        u16x8 u = *(const u16x8*)(xbb + (size_t)s * D);
#pragma unroll
        for (int j = 0; j < 8; ++j) acc[j] += bf2f(u[j]);
    }

#pragma unroll
    for (int j = 0; j < 8; ++j) {
        acc[j] += __shfl_xor(acc[j], 16, 64);
        acc[j] += __shfl_xor(acc[j], 32, 64);
    }
    if (q == 0) {                          // 16 lanes x 16B = 256B contiguous
        u16x8 u;
#pragma unroll
        for (int j = 0; j < 8; ++j) u[j] = f2bf(acc[j]);
        *(u16x8*)(aggb + (size_t)node * D + c8) = u;
    }
}

// ---------------------------------------------------------------------------
// MFMA GEMM (r0-session verified): out[n][o] = relu(sum_k aggb[n][k]*W[o][k])
// + x[n][o]. A-fragments direct from global bf16 agg; B = W row-major staged
// to LDS; residual read from xb (bf16).
// ---------------------------------------------------------------------------
__global__ void __launch_bounds__(256)
gemm_relu_res(const ushort* __restrict__ aggb,
              const float* __restrict__ W,
              const ushort* __restrict__ xb,
              float* __restrict__ out) {
    __shared__ __align__(16) char lds[33792];
    ushort* Wl = (ushort*)lds;                   // chunk-major [k/8][o][8]

    const int tid  = threadIdx.x;
    const int lane = tid & 63;
    const int wv   = tid >> 6;
    const int m16  = lane & 15;
    const int q    = lane >> 4;

#pragma unroll
    for (int i = 0; i < 8; ++i) {
        int g  = tid + i * 256;
        int o  = g & 127;
        int kc = g >> 7;
        const float4* wp = (const float4*)(W + (size_t)o * D + kc * 8);
        float4 w0 = wp[0], w1 = wp[1];
        bf16x8 hv;
        hv[0] = (short)f2bf(w0.x); hv[1] = (short)f2bf(w0.y);
        hv[2] = (short)f2bf(w0.z); hv[3] = (short)f2bf(w0.w);
        hv[4] = (short)f2bf(w1.x); hv[5] = (short)f2bf(w1.y);
        hv[6] = (short)f2bf(w1.z); hv[7] = (short)f2bf(w1.w);
        *(bf16x8*)&Wl[g * 8] = hv;
    }
    __syncthreads();

    const int nb = blockIdx.x * 64 + wv * 16;
    int arow = nb + m16;
    if (arow >= N_NODES) arow = N_NODES - 1;     // clamp: rows >= N never stored

    bf16x8 a[4];
#pragma unroll
    for (int kb = 0; kb < 4; ++kb)
        a[kb] = *(const bf16x8*)&aggb[(size_t)arow * D + kb * 32 + q * 8];

    f32x4 acc[8];
#pragma unroll
    for (int t = 0; t < 8; ++t) {
        acc[t] = (f32x4){0.f, 0.f, 0.f, 0.f};
#pragma unroll
        for (int kb = 0; kb < 4; ++kb) {
            bf16x8 bfr = *(const bf16x8*)&Wl[(((kb * 4 + q) * 128) + t * 16 + m16) * 8];
            acc[t] = __builtin_amdgcn_mfma_f32_16x16x32_bf16(a[kb], bfr, acc[t], 0, 0, 0);
        }
    }

    __syncthreads();                              // Wl dead after this
    float* Ew = (float*)(lds + wv * 8448);        // 16 rows x 132 floats
#pragma unroll
    for (int t = 0; t < 8; ++t)
#pragma unroll
        for (int r = 0; r < 4; ++r)
            Ew[(q * 4 + r) * 132 + t * 16 + m16] = acc[t][r];

    const int h  = lane >> 5;
    const int c4 = (lane & 31) << 2;
#pragma unroll
    for (int j = 0; j < 8; ++j) {
        int r = j * 2 + h;
        int node = nb + r;
        if (node < N_NODES) {
            float4 v  = *(const float4*)&Ew[r * 132 + c4];
            ushort4 xu = *(const ushort4*)(xb + (size_t)node * D + c4);
            float4 o;
            o.x = fmaxf(v.x, 0.f) + bf2f(xu.x);
            o.y = fmaxf(v.y, 0.f) + bf2f(xu.y);
            o.z = fmaxf(v.z, 0.f) + bf2f(xu.z);
            o.w = fmaxf(v.w, 0.f) + bf2f(xu.w);
            *(float4*)(out + (size_t)node * D + c4) = o;
        }
    }
}

// ===================== minimal fallback (tiny ws; never expected) ==========
__global__ void zero_out(float4* __restrict__ p, int n4) {
    int i = blockIdx.x * 256 + threadIdx.x;
    if (i < n4) p[i] = make_float4(0.f, 0.f, 0.f, 0.f);
}
__global__ void scatter_edges(const float* __restrict__ x,
                              const int* __restrict__ src,
                              const int* __restrict__ dst,
                              float* __restrict__ agg) {
    long long tid = (long long)blockIdx.x * 256 + threadIdx.x;
    if (tid >= (long long)N_EDGES * 32) return;
    int edge = (int)(tid >> 5);
    int c    = ((int)tid & 31) << 2;
    const float4 v = *(const float4*)(x + (size_t)src[edge] * D + c);
    float* p = agg + (size_t)dst[edge] * D + c;
    unsafeAtomicAdd(p + 0, v.x);
    unsafeAtomicAdd(p + 1, v.y);
    unsafeAtomicAdd(p + 2, v.z);
    unsafeAtomicAdd(p + 3, v.w);
}
__global__ void __launch_bounds__(256)
gemm_relu_res_f32(float* data, const float* __restrict__ W,
                  const float* __restrict__ x) {
    __shared__ __align__(16) char lds[50176];
    ushort* Wl = (ushort*)lds;
    ushort* Al = (ushort*)(lds + 32768);
    const int tid  = threadIdx.x;
    const int lane = tid & 63;
    const int wv   = tid >> 6;
    const int m16  = lane & 15;
    const int q    = lane >> 4;
#pragma unroll
    for (int i = 0; i < 8; ++i) {
        int g  = tid + i * 256;
        int o  = g & 127;
        int kc = g >> 7;
        const float4* wp = (const float4*)(W + (size_t)o * D + kc * 8);
        float4 w0 = wp[0], w1 = wp[1];
        bf16x8 hv;
        hv[0] = (short)f2bf(w0.x); hv[1] = (short)f2bf(w0.y);
        hv[2] = (short)f2bf(w0.z); hv[3] = (short)f2bf(w0.w);
        hv[4] = (short)f2bf(w1.x); hv[5] = (short)f2bf(w1.y);
        hv[6] = (short)f2bf(w1.z); hv[7] = (short)f2bf(w1.w);
        *(bf16x8*)&Wl[g * 8] = hv;
    }
    __syncthreads();
    const int nb = blockIdx.x * 64 + wv * 16;
    ushort* Aw = &Al[wv * (16 * 136)];
#pragma unroll
    for (int m = 0; m < 16; ++m) {
        int node = nb + m;
        float2 v = make_float2(0.f, 0.f);
        if (node < N_NODES)
            v = *(const float2*)(data + (size_t)node * D + lane * 2);
        *(ushort2*)&Aw[m * 136 + lane * 2] = make_ushort2(f2bf(v.x), f2bf(v.y));
    }
    bf16x8 a[4];
#pragma unroll
    for (int kb = 0; kb < 4; ++kb)
        a[kb] = *(const bf16x8*)&Aw[m16 * 136 + kb * 32 + q * 8];
    f32x4 acc[8];
#pragma unroll
    for (int t = 0; t < 8; ++t) {
        acc[t] = (f32x4){0.f, 0.f, 0.f, 0.f};
#pragma unroll
        for (int kb = 0; kb < 4; ++kb) {
            bf16x8 bfr = *(const bf16x8*)&Wl[(((kb * 4 + q) * 128) + t * 16 + m16) * 8];
            acc[t] = __builtin_amdgcn_mfma_f32_16x16x32_bf16(a[kb], bfr, acc[t], 0, 0, 0);
        }
    }
    __syncthreads();
    float* Ew = (float*)(lds + wv * 8448);
#pragma unroll
    for (int t = 0; t < 8; ++t)
#pragma unroll
        for (int r = 0; r < 4; ++r)
            Ew[(q * 4 + r) * 132 + t * 16 + m16] = acc[t][r];
    const int h  = lane >> 5;
    const int c4 = (lane & 31) << 2;
#pragma unroll
    for (int j = 0; j < 8; ++j) {
        int r = j * 2 + h;
        int node = nb + r;
        if (node < N_NODES) {
            float4 v  = *(const float4*)&Ew[r * 132 + c4];
            float4 xi = *(const float4*)(x + (size_t)node * D + c4);
            float4 o;
            o.x = fmaxf(v.x, 0.f) + xi.x;
            o.y = fmaxf(v.y, 0.f) + xi.y;
            o.z = fmaxf(v.z, 0.f) + xi.z;
            o.w = fmaxf(v.w, 0.f) + xi.w;
            *(float4*)(data + (size_t)node * D + c4) = o;
        }
    }
}

extern "C" void kernel_launch(void* const* d_in, const int* in_sizes, int n_in,
                              void* d_out, int out_size, void* d_ws, size_t ws_size,
                              hipStream_t stream) {
    const float* x   = (const float*)d_in[0];
    const int*   src = (const int*)d_in[1];   // harness passes integers as int32
    const int*   dst = (const int*)d_in[2];
    const float* W   = (const float*)d_in[3];
    float* out = (float*)d_out;

    char* ws = (char*)d_ws;
    int*      bcnt  = (int*)ws;      ws += (size_t)SBP * 64;               // 200 KB
    unsigned* pairs = (unsigned*)ws; ws += (size_t)SB * WCAP16 * 4;        // 4.8 MB
    ushort*   xb    = (ushort*)ws;   ws += (size_t)N_NODES * D * 2;        // 12.8 MB
    ushort*   aggb  = (ushort*)ws;   ws += (size_t)N_NODES * D * 2;        // 12.8 MB
    const bool big_ws = (ws_size >= (size_t)(ws - (char*)d_ws));

    if (big_ws) {
        hipMemsetAsync(bcnt, 0, (size_t)SBP * 64, stream);   // 200 KB fill
        convert_scatter<<<SBLK + XBLK, 1024, 0, stream>>>(
            (const float4*)x, xb, src, dst, bcnt, pairs);
        gather_sum<<<N_NODES / 4, 256, 0, stream>>>(pairs, bcnt, xb, aggb);
        gemm_relu_res<<<(N_NODES + 63) / 64, 256, 0, stream>>>(aggb, W, xb, out);
    } else {
        // slow-but-correct fallback (no scratch needed beyond d_out)
        int n4 = N_NODES * D / 4;
        zero_out<<<(n4 + 255) / 256, 256, 0, stream>>>((float4*)out, n4);
        long long n_scatter = (long long)N_EDGES * 32;
        scatter_edges<<<(int)((n_scatter + 255) / 256), 256, 0, stream>>>(
            x, src, dst, out);
        gemm_relu_res_f32<<<(N_NODES + 63) / 64, 256, 0, stream>>>(out, W, x);
    }
}

// Round 9
// 132.912 us; speedup vs baseline: 1.1643x; 1.1643x over previous
//
#include <hip/hip_runtime.h>
#include <hip/hip_bf16.h>

#define N_NODES 50000
#define N_EDGES 800000
#define D 128

#define NBUCK64 782      // scatter bucket = dst>>6 (64 nodes); 49999>>6 = 781
#define WCAP    2048     // window slots/bucket; lambda=1023, sd~32 -> huge margin
#define NGATH   3125     // gather blocks: 16 nodes each; 50000 = 3125*16

#define EPB   12288      // edges per scatter block (12*1024)
#define SBLK  66         // ceil(800000/12288); last block 1280 edges
#define CONV_BLOCKS 3200

using bf16x8 = __attribute__((ext_vector_type(8))) short;   // 8 bf16 (4 VGPRs)
using u16x8  = __attribute__((ext_vector_type(8))) unsigned short;
using f32x4  = __attribute__((ext_vector_type(4))) float;   // MFMA C/D

static __device__ __forceinline__ ushort f2bf(float f) {
    __hip_bfloat16 h = __float2bfloat16(f);   // RNE
    return *reinterpret_cast<ushort*>(&h);
}
static __device__ __forceinline__ float bf2f(ushort u) {
    return __uint_as_float(((unsigned)u) << 16);
}

// ---------------------------------------------------------------------------
// ws layout (~19.2 MB): bcnt[1024] int (4 KB), pairs[782*2048] u32 (6.4 MB,
// pack src | dst<<16), xb (bf16 x, 12.8 MB), wb (bf16 W chunk-major, 32 KB).
// r8 lesson: gather time is invariant across pipeline depth (4/8/16 loads in
// flight all ~55us) -> per-CU miss queue saturated; the lever is L2 HIT RATE.
// This round: per-node edge lists ordered by src-chunk (src>>13, 2MB slices)
// so the whole grid walks xb in the same chunk order -> L2-resident phase.
// ---------------------------------------------------------------------------

// Pure streaming: x -> bf16 + W -> bf16 chunk-major + zero bcnt (no memset).
__global__ void __launch_bounds__(256)
convert_x_w(const float4* __restrict__ x4, ushort* __restrict__ xb,
            const float* __restrict__ W, ushort* __restrict__ wb,
            int* __restrict__ bcnt) {
    const int gt = blockIdx.x * 256 + threadIdx.x;

    if (gt < 1024) bcnt[gt] = 0;           // scatter counters (runs before it)

    if (gt < 2048) {                       // W: 2048 chunks of 8
        int o  = gt & 127;
        int kc = gt >> 7;
        const float4* wp = (const float4*)(W + (size_t)o * D + kc * 8);
        float4 w0 = wp[0], w1 = wp[1];
        bf16x8 hv;
        hv[0] = (short)f2bf(w0.x); hv[1] = (short)f2bf(w0.y);
        hv[2] = (short)f2bf(w0.z); hv[3] = (short)f2bf(w0.w);
        hv[4] = (short)f2bf(w1.x); hv[5] = (short)f2bf(w1.y);
        hv[6] = (short)f2bf(w1.z); hv[7] = (short)f2bf(w1.w);
        *(bf16x8*)&wb[gt * 8] = hv;
    }

    const int total4 = N_NODES * D / 4;    // 1.6M
    const int stride = CONV_BLOCKS * 256;  // 819200
    for (int j = gt; j < total4; j += stride) {
        float4 v = x4[j];
        ushort4 u = make_ushort4(f2bf(v.x), f2bf(v.y), f2bf(v.z), f2bf(v.w));
        *(ushort4*)(xb + (size_t)j * 4) = u;
    }
}

// Counting-sort scatter: LDS histogram -> scan -> LDS place -> one atomic
// claim per (block,bucket) -> COALESCED run writes. 66 blocks x 1024 thr.
__global__ void __launch_bounds__(1024)
scatter_radix(const int* __restrict__ src, const int* __restrict__ dst,
              int* __restrict__ bcnt, unsigned* __restrict__ pairs) {
    __shared__ int      hist[1024];        // cnt -> inclusive scan -> lbase
    __shared__ int      lcur[1024];
    __shared__ int      gbase[1024];
    __shared__ unsigned payload[EPB];      // 48 KB; total LDS 60 KB
    const int tid  = threadIdx.x;
    const int base = blockIdx.x * EPB;
    int nblk = N_EDGES - base;
    if (nblk > EPB) nblk = EPB;

    hist[tid] = 0;
    __syncthreads();

    unsigned pk[12];
#pragma unroll
    for (int k = 0; k < 12; ++k) {
        int i = k * 1024 + tid;
        pk[k] = 0xFFFFFFFFu;               // sentinel
        if (i < nblk) {
            int e = base + i;
            pk[k] = (unsigned)src[e] | ((unsigned)dst[e] << 16);
            atomicAdd(&hist[pk[k] >> 22], 1);   // bkt = dst>>6
        }
    }
    __syncthreads();

    int v = hist[tid];                     // this bucket's count
    for (int off = 1; off < 1024; off <<= 1) {   // inclusive scan, in-place
        int t = (tid >= off) ? hist[tid - off] : 0;
        __syncthreads();
        hist[tid] += t;
        __syncthreads();
    }
    int excl = hist[tid] - v;
    __syncthreads();
    hist[tid] = excl;                      // lbase
    lcur[tid] = excl;
    gbase[tid] = (v > 0) ? atomicAdd(&bcnt[tid], v) : 0;  // only tid<782 has v>0
    __syncthreads();

#pragma unroll
    for (int k = 0; k < 12; ++k) {
        unsigned p = pk[k];
        if (p != 0xFFFFFFFFu) {
            int pos = atomicAdd(&lcur[p >> 22], 1);
            payload[pos] = p;
        }
    }
    __syncthreads();

#pragma unroll
    for (int k = 0; k < 12; ++k) {         // coalesced run writes
        int i = k * 1024 + tid;
        if (i < nblk) {
            unsigned p  = payload[i];
            int bkt = p >> 22;
            int pos = gbase[bkt] + (i - hist[bkt]);
            if (pos < WCAP)                // never trips (16-sd margin)
                pairs[bkt * WCAP + pos] = p;
        }
    }
}

// ---------------------------------------------------------------------------
// Fused gather+GEMM per 16-node sub-bucket (3125 blocks, 256 thr, 4 waves).
// CSR build keys on (node, src>>13): per-node lists come out ORDERED BY
// SRC-CHUNK (7 x 2MB slices of xb), so the whole grid reads xb in the same
// chunk order -> L2-resident working set, miss latency collapses. The gather
// inner loop is unchanged (node range is contiguous). LDS 8448 B.
//   phase 1: lsrc [1024] ushort [0,2048) | aggL [16][136] bf16 [2048,6400)
//            lcnt128/lbeg128/lcur128 [128] int each [6400,7936)
//   phase 2: Ew [16][132] float [0,8448) (aliased after barrier)
// ---------------------------------------------------------------------------
__global__ void __launch_bounds__(256)
gather_gemm(const unsigned* __restrict__ pairs, const int* __restrict__ bcnt,
            const ushort* __restrict__ xb, const ushort* __restrict__ wb,
            float* __restrict__ out) {
    __shared__ __align__(16) char lds[8448];
    ushort* lsrc    = (ushort*)lds;                  // [1024]
    ushort* aggL    = (ushort*)(lds + 2048);         // [16][136]
    int*    lcnt128 = (int*)(lds + 6400);            // [128] (node,chunk)
    int*    lbeg128 = (int*)(lds + 6912);            // [128]
    int*    lcur128 = (int*)(lds + 7424);            // [128]
    float*  Ew      = (float*)lds;                   // aliased, phase 2

    const int b    = blockIdx.x;
    const int tid  = threadIdx.x;
    const int lane = tid & 63;
    const int wv   = tid >> 6;
    const int m16  = lane & 15;
    const int q    = lane >> 4;

    const int bkt = b >> 2;                // 64-node bucket
    const unsigned s = (unsigned)(b & 3);  // sub-bucket (16 nodes)
    int cnt = bcnt[bkt];
    if (cnt > WCAP) cnt = WCAP;

    // ---- window -> regs (coalesced) ----
    unsigned w[8];
#pragma unroll
    for (int k = 0; k < 8; ++k) {
        int i = tid + k * 256;
        w[k] = (i < cnt) ? pairs[bkt * WCAP + i] : 0xFFFFFFFFu;
    }

    // ---- CSR build keyed on (node, src-chunk): filter -> hist -> scan ----
    if (tid < 128) lcnt128[tid] = 0;
    __syncthreads();
#pragma unroll
    for (int k = 0; k < 8; ++k)
        if (w[k] != 0xFFFFFFFFu && ((w[k] >> 20) & 3u) == s) {
            int key = (int)((w[k] >> 16) & 15u) * 8 + (int)((w[k] & 0xFFFFu) >> 13);
            atomicAdd(&lcnt128[key], 1);
        }
    __syncthreads();
    if (tid < 64) {                        // 128-entry scan: 2 elems/lane
        int v0 = lcnt128[tid], v1 = lcnt128[64 + tid];
        int s0 = v0;
#pragma unroll
        for (int o = 1; o < 64; o <<= 1) {
            int t = __shfl_up(s0, o, 64);
            if (tid >= o) s0 += t;
        }
        int tot0 = __shfl(s0, 63, 64);
        int s1 = v1;
#pragma unroll
        for (int o = 1; o < 64; o <<= 1) {
            int t = __shfl_up(s1, o, 64);
            if (tid >= o) s1 += t;
        }
        s1 += tot0;
        lbeg128[tid]      = s0 - v0;  lcur128[tid]      = s0 - v0;
        lbeg128[64 + tid] = s1 - v1;  lcur128[64 + tid] = s1 - v1;
    }
    __syncthreads();
#pragma unroll
    for (int k = 0; k < 8; ++k)
        if (w[k] != 0xFFFFFFFFu && ((w[k] >> 20) & 3u) == s) {
            int key = (int)((w[k] >> 16) & 15u) * 8 + (int)((w[k] & 0xFFFFu) >> 13);
            int pos = atomicAdd(&lcur128[key], 1);
            if (pos < 1024) lsrc[pos] = (ushort)(w[k] & 0xFFFFu);
        }
    __syncthreads();                       // node n range = [lbeg[n*8], lcur[n*8+7])

    // ---- gather: wave wv owns nodes wv*4..wv*4+3; two-node interleave ----
    const int c8 = m16 << 3;               // bf16 col 0,8,..,120
    const ushort* xbb = xb + c8;

    auto drain = [&](int t, int e, float* acc) {
        for (; t + 8 <= e; t += 8) {
            int s0 = lsrc[t + q];
            int s1v = lsrc[t + 4 + q];
            u16x8 u0 = *(const u16x8*)(xbb + (size_t)s0 * D);
            u16x8 u1 = *(const u16x8*)(xbb + (size_t)s1v * D);
#pragma unroll
            for (int j = 0; j < 8; ++j) acc[j] += bf2f(u0[j]) + bf2f(u1[j]);
        }
        for (; t + 4 <= e; t += 4) {
            int sv = lsrc[t + q];
            u16x8 u = *(const u16x8*)(xbb + (size_t)sv * D);
#pragma unroll
            for (int j = 0; j < 8; ++j) acc[j] += bf2f(u[j]);
        }
        const int rem = e - t;
        if (rem && q < rem) {
            int sv = lsrc[t + q];
            u16x8 u = *(const u16x8*)(xbb + (size_t)sv * D);
#pragma unroll
            for (int j = 0; j < 8; ++j) acc[j] += bf2f(u[j]);
        }
    };
    auto red_store = [&](int nloc, float* acc) {
#pragma unroll
        for (int j = 0; j < 8; ++j) {
            acc[j] += __shfl_xor(acc[j], 16, 64);
            acc[j] += __shfl_xor(acc[j], 32, 64);
        }
        if (q == 0) {
            u16x8 u;
#pragma unroll
            for (int j = 0; j < 8; ++j) u[j] = f2bf(acc[j]);
            *(u16x8*)&aggL[(size_t)nloc * 136 + c8] = u;
        }
    };

#pragma unroll 1
    for (int pm = 0; pm < 2; ++pm) {
        const int nA = wv * 4 + pm * 2;
        const int nB = nA + 1;
        int tA = lbeg128[nA * 8]; int eA = lcur128[nA * 8 + 7];
        int tB = lbeg128[nB * 8]; int eB = lcur128[nB * 8 + 7];
        if (eA > 1024) eA = 1024;          // astronomically-improbable clamps
        if (eB > 1024) eB = 1024;
        float accA[8], accB[8];
#pragma unroll
        for (int j = 0; j < 8; ++j) { accA[j] = 0.f; accB[j] = 0.f; }

        while (tA + 8 <= eA && tB + 8 <= eB) {   // 4 loads in flight
            int a0 = lsrc[tA + q], a1 = lsrc[tA + 4 + q];
            int b0 = lsrc[tB + q], b1 = lsrc[tB + 4 + q];
            u16x8 uA0 = *(const u16x8*)(xbb + (size_t)a0 * D);
            u16x8 uA1 = *(const u16x8*)(xbb + (size_t)a1 * D);
            u16x8 uB0 = *(const u16x8*)(xbb + (size_t)b0 * D);
            u16x8 uB1 = *(const u16x8*)(xbb + (size_t)b1 * D);
#pragma unroll
            for (int j = 0; j < 8; ++j) {
                accA[j] += bf2f(uA0[j]) + bf2f(uA1[j]);
                accB[j] += bf2f(uB0[j]) + bf2f(uB1[j]);
            }
            tA += 8; tB += 8;
        }
        while (tA + 4 <= eA && tB + 4 <= eB) {   // 2 in flight
            int a0 = lsrc[tA + q], b0 = lsrc[tB + q];
            u16x8 uA = *(const u16x8*)(xbb + (size_t)a0 * D);
            u16x8 uB = *(const u16x8*)(xbb + (size_t)b0 * D);
#pragma unroll
            for (int j = 0; j < 8; ++j) {
                accA[j] += bf2f(uA[j]);
                accB[j] += bf2f(uB[j]);
            }
            tA += 4; tB += 4;
        }
        drain(tA, eA, accA);
        drain(tB, eB, accB);
        red_store(nA, accA);
        red_store(nB, accB);
    }
    __syncthreads();                       // aggL complete

    // ---- MFMA GEMM: out[n][o] = relu(sum_k agg[n][k]*W[o][k]) + x[n][o] ----
    bf16x8 a[4];
#pragma unroll
    for (int kb = 0; kb < 4; ++kb)
        a[kb] = *(const bf16x8*)&aggL[(size_t)m16 * 136 + kb * 32 + q * 8];
    __syncthreads();                       // A-frags read: Ew may alias

    f32x4 acc[2];
#pragma unroll
    for (int tt = 0; tt < 2; ++tt) {
        const int t = wv * 2 + tt;
        acc[tt] = (f32x4){0.f, 0.f, 0.f, 0.f};
#pragma unroll
        for (int kb = 0; kb < 4; ++kb) {
            bf16x8 bfr = *(const bf16x8*)&wb[(((kb * 4 + q) * 128) + t * 16 + m16) * 8];
            acc[tt] = __builtin_amdgcn_mfma_f32_16x16x32_bf16(a[kb], bfr, acc[tt], 0, 0, 0);
        }
    }

#pragma unroll
    for (int tt = 0; tt < 2; ++tt) {
        const int t = wv * 2 + tt;
#pragma unroll
        for (int r = 0; r < 4; ++r)
            Ew[(q * 4 + r) * 132 + t * 16 + m16] = acc[tt][r];
    }
    __syncthreads();                       // Ew complete (cross-wave cols)

    // ---- epilogue: relu + residual, 2 float4 per thread, coalesced ----
#pragma unroll
    for (int k = 0; k < 2; ++k) {
        int idx = tid + k * 256;
        int row = idx >> 5;                // 0..15
        int c4  = (idx & 31) << 2;         // f32 col 0,4,..,124
        int node = b * 16 + row;           // < 50000 always
        float4 v  = *(const float4*)&Ew[row * 132 + c4];
        ushort4 xu = *(const ushort4*)(xb + (size_t)node * D + c4);
        float4 o;
        o.x = fmaxf(v.x, 0.f) + bf2f(xu.x);
        o.y = fmaxf(v.y, 0.f) + bf2f(xu.y);
        o.z = fmaxf(v.z, 0.f) + bf2f(xu.z);
        o.w = fmaxf(v.w, 0.f) + bf2f(xu.w);
        *(float4*)(out + (size_t)node * D + c4) = o;
    }
}

// ===================== minimal fallback (tiny ws; never expected) ==========
__global__ void zero_out(float4* __restrict__ p, int n4) {
    int i = blockIdx.x * 256 + threadIdx.x;
    if (i < n4) p[i] = make_float4(0.f, 0.f, 0.f, 0.f);
}
__global__ void scatter_edges(const float* __restrict__ x,
                              const int* __restrict__ src,
                              const int* __restrict__ dst,
                              float* __restrict__ agg) {
    long long tid = (long long)blockIdx.x * 256 + threadIdx.x;
    if (tid >= (long long)N_EDGES * 32) return;
    int edge = (int)(tid >> 5);
    int c    = ((int)tid & 31) << 2;
    const float4 v = *(const float4*)(x + (size_t)src[edge] * D + c);
    float* p = agg + (size_t)dst[edge] * D + c;
    unsafeAtomicAdd(p + 0, v.x);
    unsafeAtomicAdd(p + 1, v.y);
    unsafeAtomicAdd(p + 2, v.z);
    unsafeAtomicAdd(p + 3, v.w);
}
__global__ void __launch_bounds__(256)
gemm_relu_res_f32(float* data, const float* __restrict__ W,
                  const float* __restrict__ x) {
    __shared__ __align__(16) char lds[50176];
    ushort* Wl = (ushort*)lds;
    ushort* Al = (ushort*)(lds + 32768);
    const int tid  = threadIdx.x;
    const int lane = tid & 63;
    const int wv   = tid >> 6;
    const int m16  = lane & 15;
    const int q    = lane >> 4;
#pragma unroll
    for (int i = 0; i < 8; ++i) {
        int g  = tid + i * 256;
        int o  = g & 127;
        int kc = g >> 7;
        const float4* wp = (const float4*)(W + (size_t)o * D + kc * 8);
        float4 w0 = wp[0], w1 = wp[1];
        bf16x8 hv;
        hv[0] = (short)f2bf(w0.x); hv[1] = (short)f2bf(w0.y);
        hv[2] = (short)f2bf(w0.z); hv[3] = (short)f2bf(w0.w);
        hv[4] = (short)f2bf(w1.x); hv[5] = (short)f2bf(w1.y);
        hv[6] = (short)f2bf(w1.z); hv[7] = (short)f2bf(w1.w);
        *(bf16x8*)&Wl[g * 8] = hv;
    }
    __syncthreads();
    const int nb = blockIdx.x * 64 + wv * 16;
    ushort* Aw = &Al[wv * (16 * 136)];
#pragma unroll
    for (int m = 0; m < 16; ++m) {
        int node = nb + m;
        float2 v = make_float2(0.f, 0.f);
        if (node < N_NODES)
            v = *(const float2*)(data + (size_t)node * D + lane * 2);
        *(ushort2*)&Aw[m * 136 + lane * 2] = make_ushort2(f2bf(v.x), f2bf(v.y));
    }
    bf16x8 a[4];
#pragma unroll
    for (int kb = 0; kb < 4; ++kb)
        a[kb] = *(const bf16x8*)&Aw[m16 * 136 + kb * 32 + q * 8];
    f32x4 acc[8];
#pragma unroll
    for (int t = 0; t < 8; ++t) {
        acc[t] = (f32x4){0.f, 0.f, 0.f, 0.f};
#pragma unroll
        for (int kb = 0; kb < 4; ++kb) {
            bf16x8 bfr = *(const bf16x8*)&Wl[(((kb * 4 + q) * 128) + t * 16 + m16) * 8];
            acc[t] = __builtin_amdgcn_mfma_f32_16x16x32_bf16(a[kb], bfr, acc[t], 0, 0, 0);
        }
    }
    __syncthreads();
    float* Ew = (float*)(lds + wv * 8448);
#pragma unroll
    for (int t = 0; t < 8; ++t)
#pragma unroll
        for (int r = 0; r < 4; ++r)
            Ew[(q * 4 + r) * 132 + t * 16 + m16] = acc[t][r];
    const int h  = lane >> 5;
    const int c4 = (lane & 31) << 2;
#pragma unroll
    for (int j = 0; j < 8; ++j) {
        int r = j * 2 + h;
        int node = nb + r;
        if (node < N_NODES) {
            float4 v  = *(const float4*)&Ew[r * 132 + c4];
            float4 xi = *(const float4*)(x + (size_t)node * D + c4);
            float4 o;
            o.x = fmaxf(v.x, 0.f) + xi.x;
            o.y = fmaxf(v.y, 0.f) + xi.y;
            o.z = fmaxf(v.z, 0.f) + xi.z;
            o.w = fmaxf(v.w, 0.f) + xi.w;
            *(float4*)(data + (size_t)node * D + c4) = o;
        }
    }
}

extern "C" void kernel_launch(void* const* d_in, const int* in_sizes, int n_in,
                              void* d_out, int out_size, void* d_ws, size_t ws_size,
                              hipStream_t stream) {
    const float* x   = (const float*)d_in[0];
    const int*   src = (const int*)d_in[1];   // harness passes integers as int32
    const int*   dst = (const int*)d_in[2];
    const float* W   = (const float*)d_in[3];
    float* out = (float*)d_out;

    char* ws = (char*)d_ws;
    int*      bcnt  = (int*)ws;      ws += (size_t)1024 * 4;               // 4 KB
    unsigned* pairs = (unsigned*)ws; ws += (size_t)NBUCK64 * WCAP * 4;     // 6.4 MB
    ushort*   xb    = (ushort*)ws;   ws += (size_t)N_NODES * D * 2;        // 12.8 MB
    ushort*   wb    = (ushort*)ws;   ws += (size_t)D * D * 2;              // 32 KB
    const bool big_ws = (ws_size >= (size_t)(ws - (char*)d_ws));

    if (big_ws) {
        convert_x_w<<<CONV_BLOCKS, 256, 0, stream>>>(
            (const float4*)x, xb, W, wb, bcnt);
        scatter_radix<<<SBLK, 1024, 0, stream>>>(src, dst, bcnt, pairs);
        gather_gemm<<<NGATH, 256, 0, stream>>>(pairs, bcnt, xb, wb, out);
    } else {
        // slow-but-correct fallback (no scratch needed beyond d_out)
        int n4 = N_NODES * D / 4;
        zero_out<<<(n4 + 255) / 256, 256, 0, stream>>>((float4*)out, n4);
        long long n_scatter = (long long)N_EDGES * 32;
        scatter_edges<<<(int)((n_scatter + 255) / 256), 256, 0, stream>>>(
            x, src, dst, out);
        gemm_relu_res_f32<<<(N_NODES + 63) / 64, 256, 0, stream>>>(out, W, x);
    }
}